// Round 9
// baseline (410.932 us; speedup 1.0000x reference)
//
#include <hip/hip_runtime.h>
#include <hip/hip_bf16.h>
#include <hip/hip_fp16.h>

#define NNODES 100000
#define NEDGES 1600000
#define NHEADS 4
#define NHID   16
#define NB     64
#define NG     16
#define POOL_BLOCKS 128
#define POOL_SLOTS (NB * NG + NB)   // 1088: [64x16 pooled | 64 counts]

// CSR counting-sort parameters
#define BKT_SHIFT 7
#define NPB 128                               // nodes per bucket
#define NBKT ((NNODES + NPB - 1) / NPB)       // 782
#define BCAP 4096                             // per-bucket capacity (mean ~2046)
#define SCAT_BLOCKS 128                       // fewer blocks: longer runs, less
                                              // bucketCnt atomic contention

__device__ __forceinline__ float leaky02(float v) {
    return v > 0.0f ? v : 0.2f * v;
}

// load 4 consecutive halves as float4 (8-byte aligned)
__device__ __forceinline__ float4 loadH4(const __half* p) {
    uint2 raw = *(const uint2*)p;
    __half2 a = *reinterpret_cast<const __half2*>(&raw.x);
    __half2 b = *reinterpret_cast<const __half2*>(&raw.y);
    float2 fa = __half22float2(a), fb = __half22float2(b);
    return make_float4(fa.x, fa.y, fb.x, fb.y);
}

__device__ __forceinline__ void storeH4(__half* p, float4 v) {
    __half2 a = __floats2half2_rn(v.x, v.y);
    __half2 b = __floats2half2_rn(v.z, v.w);
    uint2 raw;
    raw.x = *reinterpret_cast<unsigned*>(&a);
    raw.y = *reinterpret_cast<unsigned*>(&b);
    *(uint2*)p = raw;
}

// ---------------------------------------------------------------------------
// node_linear v3: wave-per-node, lane = output channel (h*16+c).
// Node index wave-uniform (readfirstlane) -> x row via scalar loads.
// TIN float or __half; H stored fp16; AS/AD fp32.
// ---------------------------------------------------------------------------
template <int FIN, typename TIN>
__global__ void node_linear3(const TIN* __restrict__ X,
                             const float* __restrict__ W,
                             const float* __restrict__ a_s,
                             const float* __restrict__ a_d,
                             __half* __restrict__ H,
                             float* __restrict__ AS,
                             float* __restrict__ AD, int n) {
    int lane = threadIdx.x & 63;
    int head = lane >> 4;
    int wave = __builtin_amdgcn_readfirstlane(
        (int)((blockIdx.x * blockDim.x + threadIdx.x) >> 6));
    int nwaves = (gridDim.x * blockDim.x) >> 6;

    float w[FIN];
#pragma unroll
    for (int k = 0; k < FIN; ++k) w[k] = W[k * 64 + lane];
    float asl = a_s[lane], adl = a_d[lane];

    for (int i = wave; i < n; i += nwaves) {
        const TIN* __restrict__ xr = X + (size_t)i * FIN;  // uniform address
        float acc = 0.0f;
#pragma unroll
        for (int k = 0; k < FIN; ++k) acc += (float)xr[k] * w[k];
        H[(size_t)i * 64 + lane] = __float2half_rn(acc);
        float s1 = acc * asl, s2 = acc * adl;
#pragma unroll
        for (int off = 1; off < 16; off <<= 1) {
            s1 += __shfl_xor(s1, off);
            s2 += __shfl_xor(s2, off);
        }
        if ((lane & 15) == 0) {
            AS[(size_t)i * 4 + head] = s1;
            AD[(size_t)i * 4 + head] = s2;
        }
    }
}

// ---------------------------------------------------------------------------
// CSR build: two-level counting sort. No fine-grained global scatter.
// pairs[bkt*BCAP + r] = src | (dst_local << 20)   (src < 2^17, dl < 2^7)
// ---------------------------------------------------------------------------
__global__ void bucket_scatter(const int* __restrict__ src,
                               const int* __restrict__ dst,
                               int* __restrict__ bucketCnt,
                               unsigned int* __restrict__ pairs, int ne) {
    __shared__ int hist[NBKT];
    __shared__ int base[NBKT];
    int tid = threadIdx.x;
    for (int i = tid; i < NBKT; i += 256) hist[i] = 0;
    __syncthreads();

    int chunk = (ne + gridDim.x - 1) / gridDim.x;
    int beg = blockIdx.x * chunk;
    int end = min(beg + chunk, ne);

    for (int e = beg + tid; e < end; e += 256)
        atomicAdd(&hist[dst[e] >> BKT_SHIFT], 1);
    __syncthreads();

    for (int i = tid; i < NBKT; i += 256) {
        int h = hist[i];
        base[i] = h ? atomicAdd(&bucketCnt[i], h) : 0;  // reserve range
        hist[i] = 0;                                    // reuse as cursor
    }
    __syncthreads();

    for (int e = beg + tid; e < end; e += 256) {
        int d = dst[e];
        int bkt = d >> BKT_SHIFT;
        int r = base[bkt] + atomicAdd(&hist[bkt], 1);
        if (r < BCAP)
            pairs[(size_t)bkt * BCAP + r] =
                (unsigned)src[e] | ((unsigned)(d & (NPB - 1)) << 20);
    }
}

// one block: exclusive scan of bucket counts
__global__ void bucket_scan(const int* __restrict__ bucketCnt,
                            int* __restrict__ bucketOff,
                            int* __restrict__ indptr, int n) {
    __shared__ int sd[1024];
    int t = threadIdx.x;
    int v = (t < NBKT) ? min(bucketCnt[t], BCAP) : 0;
    sd[t] = v;
    __syncthreads();
    for (int off = 1; off < 1024; off <<= 1) {
        int x = (t >= off) ? sd[t - off] : 0;
        __syncthreads();
        if (t >= off) sd[t] += x;
        __syncthreads();
    }
    if (t < NBKT) bucketOff[t] = sd[t] - v;
    if (t == NBKT - 1) {
        bucketOff[NBKT] = sd[t];
        indptr[n] = sd[t];
    }
}

// one block per bucket: local counting sort in LDS, coalesced output
__global__ void bucket_sort(const unsigned int* __restrict__ pairs,
                            const int* __restrict__ bucketCnt,
                            const int* __restrict__ bucketOff,
                            int* __restrict__ srcs,
                            int* __restrict__ indptr, int n) {
    __shared__ int hist[NPB];
    __shared__ int offl[NPB];
    __shared__ int cur[NPB];
    __shared__ int lsrc[BCAP];
    int bkt = blockIdx.x;
    int t = threadIdx.x;
    int cnt = min(bucketCnt[bkt], BCAP);
    int boff = bucketOff[bkt];
    if (t < NPB) hist[t] = 0;
    __syncthreads();

    const unsigned int* __restrict__ p = pairs + (size_t)bkt * BCAP;
    unsigned int v[BCAP / 256];
#pragma unroll
    for (int i = 0; i < BCAP / 256; ++i) {
        int e = i * 256 + t;
        v[i] = 0u;
        if (e < cnt) {
            v[i] = p[e];
            atomicAdd(&hist[v[i] >> 20], 1);
        }
    }
    __syncthreads();
    if (t < NPB) offl[t] = hist[t];
    __syncthreads();
    for (int off = 1; off < NPB; off <<= 1) {
        int x = 0;
        if (t < NPB && t >= off) x = offl[t - off];
        __syncthreads();
        if (t < NPB && t >= off) offl[t] += x;
        __syncthreads();
    }
    if (t < NPB) {
        int ex = offl[t] - hist[t];   // exclusive
        cur[t] = ex;
        int node = bkt * NPB + t;
        if (node < n) indptr[node] = boff + ex;
    }
    __syncthreads();
#pragma unroll
    for (int i = 0; i < BCAP / 256; ++i) {
        int e = i * 256 + t;
        if (e < cnt) {
            int r = atomicAdd(&cur[v[i] >> 20], 1);
            lsrc[r] = (int)(v[i] & 0xFFFFFu);
        }
    }
    __syncthreads();
    for (int e = t; e < cnt; e += 256) srcs[boff + e] = lsrc[e];
}

// ---------------------------------------------------------------------------
// Pull-mode GAT aggregate v3: 4 dst nodes per wave, 16-lane group per node.
// Inner loop 8-wide: 8 gathers in flight. NO atomics.
// MODE 0: concat+elu -> half [n,64]; MODE 1: head-mean+elu -> float [n,16];
// MODE 2: head-mean -> float [n,16]
// ---------------------------------------------------------------------------
template <int MODE, typename TOUT>
__global__ void gat_pull3(const __half* __restrict__ H,
                          const float* __restrict__ AS,
                          const float* __restrict__ AD,
                          const int* __restrict__ indptr,
                          const int* __restrict__ srcs,
                          const float* __restrict__ bias,
                          TOUT* __restrict__ out, int n) {
    int lane = threadIdx.x & 63;
    int grp  = lane >> 4;          // which node of the quad
    int sl   = lane & 15;          // channel-quad index (channels 4sl..4sl+3)
    int head = sl >> 2;            // head of this channel quad
    int wave = (blockIdx.x * blockDim.x + threadIdx.x) >> 6;
    int nwaves = (gridDim.x * blockDim.x) >> 6;

    for (int d0 = wave * 4; d0 < n; d0 += nwaves * 4) {
        int d = d0 + grp;
        if (d < n) {
            float ad  = AD[(size_t)d * 4 + head];
            float asd = AS[(size_t)d * 4 + head];
            // self-loop
            float t0 = asd + ad;
            float wself = __expf(t0 > 0.f ? t0 : 0.2f * t0);
            float den = wself;
            float4 h4s = loadH4(H + (size_t)d * 64 + sl * 4);
            float4 acc = {wself * h4s.x, wself * h4s.y,
                          wself * h4s.z, wself * h4s.w};

            int beg = indptr[d], end = indptr[d + 1];
            for (int e0 = beg; e0 < end; e0 += 16) {
                int cnt = min(16, end - e0);
                int myS = (sl < cnt) ? srcs[e0 + sl] : 0;  // 16/group, coalesced
                int j = 0;
                for (; j + 8 <= cnt; j += 8) {             // 8 gathers in flight
                    int s[8]; float a[8]; float4 h4[8];
#pragma unroll
                    for (int q = 0; q < 8; ++q)
                        s[q] = __shfl(myS, (grp << 4) + j + q);
#pragma unroll
                    for (int q = 0; q < 8; ++q)
                        a[q] = AS[(size_t)s[q] * 4 + head];
#pragma unroll
                    for (int q = 0; q < 8; ++q)
                        h4[q] = loadH4(H + (size_t)s[q] * 64 + sl * 4);
#pragma unroll
                    for (int q = 0; q < 8; ++q) {
                        float t = a[q] + ad;
                        float w = __expf(t > 0.f ? t : 0.2f * t);
                        den += w;
                        acc.x += w * h4[q].x; acc.y += w * h4[q].y;
                        acc.z += w * h4[q].z; acc.w += w * h4[q].w;
                    }
                }
                for (; j < cnt; ++j) {                     // tail
                    int s = __shfl(myS, (grp << 4) + j);
                    float t = AS[(size_t)s * 4 + head] + ad;
                    float w = __expf(t > 0.f ? t : 0.2f * t);
                    den += w;
                    float4 h4 = loadH4(H + (size_t)s * 64 + sl * 4);
                    acc.x += w * h4.x; acc.y += w * h4.y;
                    acc.z += w * h4.z; acc.w += w * h4.w;
                }
            }
            float inv = 1.0f / (den + 1e-16f);
            float4 v = {acc.x * inv, acc.y * inv, acc.z * inv, acc.w * inv};
            if (MODE == 0) {
                float4 b4 = *(const float4*)(bias + sl * 4);
                v.x += b4.x; v.y += b4.y; v.z += b4.z; v.w += b4.w;
                v.x = v.x > 0.f ? v.x : __expf(v.x) - 1.f;
                v.y = v.y > 0.f ? v.y : __expf(v.y) - 1.f;
                v.z = v.z > 0.f ? v.z : __expf(v.z) - 1.f;
                v.w = v.w > 0.f ? v.w : __expf(v.w) - 1.f;
                storeH4((__half*)out + (size_t)d * 64 + sl * 4, v);
            } else {
                // head-mean within group: offsets 4,8 fold the 4 heads
#pragma unroll
                for (int off = 4; off <= 8; off <<= 1) {
                    v.x += __shfl_xor(v.x, off);
                    v.y += __shfl_xor(v.y, off);
                    v.z += __shfl_xor(v.z, off);
                    v.w += __shfl_xor(v.w, off);
                }
                float4 b4 = *(const float4*)(bias + (sl & 3) * 4);
                v.x = 0.25f * v.x + b4.x; v.y = 0.25f * v.y + b4.y;
                v.z = 0.25f * v.z + b4.z; v.w = 0.25f * v.w + b4.w;
                if (MODE == 1) {
                    v.x = v.x > 0.f ? v.x : __expf(v.x) - 1.f;
                    v.y = v.y > 0.f ? v.y : __expf(v.y) - 1.f;
                    v.z = v.z > 0.f ? v.z : __expf(v.z) - 1.f;
                    v.w = v.w > 0.f ? v.w : __expf(v.w) - 1.f;
                }
                if (sl < 4)
                    *(float4*)((float*)out + (size_t)d * 16 + sl * 4) = v;
            }
        }
    }
}

// ---------------------------------------------------------------------------
// Two-stage mean-pool (no global atomics)
// ---------------------------------------------------------------------------
__global__ void pool_stage1(const float* __restrict__ Hf,
                            const int* __restrict__ batch,
                            float* __restrict__ partials, int n) {
    __shared__ float lp[POOL_SLOTS];
    int tid = threadIdx.x;
    for (int i = tid; i < POOL_SLOTS; i += 256) lp[i] = 0.0f;
    __syncthreads();

    int chunk = (n + POOL_BLOCKS - 1) / POOL_BLOCKS;
    int start = blockIdx.x * chunk;
    int end = min(start + chunk, n);
    int c = tid & 15;
    for (int node = start + (tid >> 4); node < end; node += 16) {
        int b = batch[node];
        atomicAdd(&lp[b * 16 + c], Hf[(size_t)node * 16 + c]);
        if (c == 0) atomicAdd(&lp[NB * NG + b], 1.0f);
    }
    __syncthreads();
    float* outp = partials + (size_t)blockIdx.x * POOL_SLOTS;
    for (int i = tid; i < POOL_SLOTS; i += 256) outp[i] = lp[i];
}

__global__ void pool_stage2(const float* __restrict__ partials,
                            float* __restrict__ pooled_counts) {
    int idx = blockIdx.x * blockDim.x + threadIdx.x;
    if (idx >= POOL_SLOTS) return;
    float s = 0.0f;
    for (int j = 0; j < POOL_BLOCKS; ++j)
        s += partials[(size_t)j * POOL_SLOTS + idx];
    pooled_counts[idx] = s;
}

// final MLP head, one thread per graph (64 graphs)
__global__ void mlp_head(const float* __restrict__ pooled_counts,
                         const float* __restrict__ stats,
                         const float* __restrict__ fw1, const float* __restrict__ fb1,
                         const float* __restrict__ fw2, const float* __restrict__ fb2,
                         const float* __restrict__ fw3, const float* __restrict__ fb3,
                         float* __restrict__ out) {
    int g = threadIdx.x;
    if (g >= NB) return;
    const float* pooled = pooled_counts;
    const float* counts = pooled_counts + NB * NG;
    float z[32];
    float inv = 1.0f / fmaxf(counts[g], 1.0f);
#pragma unroll
    for (int c = 0; c < 16; ++c) z[c] = pooled[g * 16 + c] * inv;
#pragma unroll
    for (int c = 0; c < 16; ++c) z[16 + c] = stats[g * 16 + c];

    float z1[32];
#pragma unroll
    for (int j = 0; j < 32; ++j) {
        float acc = fb1[j];
        for (int k = 0; k < 32; ++k) acc += z[k] * fw1[k * 32 + j];
        z1[j] = fmaxf(acc, 0.0f);
    }
    float z2[16];
#pragma unroll
    for (int j = 0; j < 16; ++j) {
        float acc = fb2[j];
        for (int k = 0; k < 32; ++k) acc += z1[k] * fw2[k * 16 + j];
        z2[j] = fmaxf(acc, 0.0f);
    }
    float acc = fb3[0];
#pragma unroll
    for (int k = 0; k < 16; ++k) acc += z2[k] * fw3[k];
    out[g] = acc;
}

extern "C" void kernel_launch(void* const* d_in, const int* in_sizes, int n_in,
                              void* d_out, int out_size, void* d_ws, size_t ws_size,
                              hipStream_t stream) {
    const float* x    = (const float*)d_in[0];
    const float* stats= (const float*)d_in[1];
    const float* W1   = (const float*)d_in[2];
    const float* a1s  = (const float*)d_in[3];
    const float* a1d  = (const float*)d_in[4];
    const float* b1   = (const float*)d_in[5];
    const float* W2   = (const float*)d_in[6];
    const float* a2s  = (const float*)d_in[7];
    const float* a2d  = (const float*)d_in[8];
    const float* b2   = (const float*)d_in[9];
    const float* W3   = (const float*)d_in[10];
    const float* a3s  = (const float*)d_in[11];
    const float* a3d  = (const float*)d_in[12];
    const float* b3   = (const float*)d_in[13];
    const float* fw1  = (const float*)d_in[14];
    const float* fb1  = (const float*)d_in[15];
    const float* fw2  = (const float*)d_in[16];
    const float* fb2  = (const float*)d_in[17];
    const float* fw3  = (const float*)d_in[18];
    const float* fb3  = (const float*)d_in[19];
    const int* ei     = (const int*)d_in[20];
    const int* batch  = (const int*)d_in[21];

    const int n = NNODES, ne = NEDGES;
    const int* srcI = ei;
    const int* dstI = ei + ne;

    // ---- workspace layout ----
    float* ws = (float*)d_ws;
    __half* Hh  = (__half*)ws;                       // [n,64] fp16 = 12.8MB
    float* B    = (float*)(Hh + (size_t)n * 64);     // 25.6MB region; pairs aliases
    __half* B16 = (__half*)B;                        // layer1 out fp16 [n,64]
    float* C2   = B + (size_t)n * 64;                // [n,16]
    float* AS   = C2 + (size_t)n * 16;               // [n,4]
    float* AD   = AS + (size_t)n * 4;                // [n,4]
    float* PC   = AD + (size_t)n * 4;                // pooled_counts [1088]
    float* PART = PC + POOL_SLOTS;                   // [128][1088]
    int* bucketCnt = (int*)(PART + (size_t)POOL_BLOCKS * POOL_SLOTS); // [NBKT]
    int* bucketOff = bucketCnt + NBKT;               // [NBKT+1]
    int* indptr    = bucketOff + NBKT + 1;           // [n+1]
    int* srcs      = indptr + n + 1;                 // [ne]
    unsigned int* pairs = (unsigned int*)B;          // 12.82MB, dead before layer 1

    const int TB = 256;
    const int nlBlocks   = 2048;
    const int pullBlocks = (n + 15) / 16;            // 4 waves/blk × 4 nodes/wave

    // ---- CSR build: LDS-staged two-level counting sort ----
    hipMemsetAsync(bucketCnt, 0, NBKT * sizeof(int), stream);
    bucket_scatter<<<SCAT_BLOCKS, TB, 0, stream>>>(srcI, dstI, bucketCnt, pairs, ne);
    bucket_scan<<<1, 1024, 0, stream>>>(bucketCnt, bucketOff, indptr, n);
    bucket_sort<<<NBKT, TB, 0, stream>>>(pairs, bucketCnt, bucketOff, srcs,
                                         indptr, n);

    // ---- layer 1: 16 -> 4x16 concat, elu (fp16 out) ----
    node_linear3<16, float><<<nlBlocks, TB, 0, stream>>>(x, W1, a1s, a1d, Hh, AS, AD, n);
    gat_pull3<0, __half><<<pullBlocks, TB, 0, stream>>>(Hh, AS, AD, indptr, srcs, b1, B16, n);

    // ---- layer 2: 64 (fp16 in) -> head-mean 16, elu ----
    node_linear3<64, __half><<<nlBlocks, TB, 0, stream>>>(B16, W2, a2s, a2d, Hh, AS, AD, n);
    gat_pull3<1, float><<<pullBlocks, TB, 0, stream>>>(Hh, AS, AD, indptr, srcs, b2, C2, n);

    // ---- layer 3: 16 -> head-mean 16, no act ----
    node_linear3<16, float><<<nlBlocks, TB, 0, stream>>>(C2, W3, a3s, a3d, Hh, AS, AD, n);
    gat_pull3<2, float><<<pullBlocks, TB, 0, stream>>>(Hh, AS, AD, indptr, srcs, b3, B, n);

    // ---- two-stage pool + MLP ----
    pool_stage1<<<POOL_BLOCKS, TB, 0, stream>>>(B, batch, PART, n);
    pool_stage2<<<(POOL_SLOTS + TB - 1) / TB, TB, 0, stream>>>(PART, PC);
    mlp_head<<<1, 64, 0, stream>>>(PC, stats, fw1, fb1, fw2, fb2, fw3, fb3,
                                   (float*)d_out);
}

// Round 10
// 355.890 us; speedup vs baseline: 1.1547x; 1.1547x over previous
//
#include <hip/hip_runtime.h>
#include <hip/hip_bf16.h>
#include <hip/hip_fp16.h>

#define NNODES 100000
#define NEDGES 1600000
#define NHEADS 4
#define NHID   16
#define NB     64
#define NG     16
#define POOL_BLOCKS 128
#define POOL_SLOTS (NB * NG + NB)   // 1088: [64x16 pooled | 64 counts]

// CSR counting-sort parameters
#define BKT_SHIFT 7
#define NPB 128                               // nodes per bucket
#define NBKT ((NNODES + NPB - 1) / NPB)       // 782
#define BCAP 4096                             // per-bucket capacity (mean ~2046)
#define SCAT_BLOCKS 512                       // latency-bound: more waves = faster
#define NL1_BLOCKS 2048

__device__ __forceinline__ float leaky02(float v) {
    return v > 0.0f ? v : 0.2f * v;
}

// load 4 consecutive halves as float4 (8-byte aligned)
__device__ __forceinline__ float4 loadH4(const __half* p) {
    uint2 raw = *(const uint2*)p;
    __half2 a = *reinterpret_cast<const __half2*>(&raw.x);
    __half2 b = *reinterpret_cast<const __half2*>(&raw.y);
    float2 fa = __half22float2(a), fb = __half22float2(b);
    return make_float4(fa.x, fa.y, fb.x, fb.y);
}

__device__ __forceinline__ void storeH4(__half* p, float4 v) {
    __half2 a = __floats2half2_rn(v.x, v.y);
    __half2 b = __floats2half2_rn(v.z, v.w);
    uint2 raw;
    raw.x = *reinterpret_cast<unsigned*>(&a);
    raw.y = *reinterpret_cast<unsigned*>(&b);
    *(uint2*)p = raw;
}

// ---------------------------------------------------------------------------
// node_linear device bodies: wave-per-node, lane = output channel (h*16+c).
// Node index wave-uniform (readfirstlane) -> x row via SCALAR loads.
// fp32 input variant:
// ---------------------------------------------------------------------------
template <int FIN>
__device__ __forceinline__ void nl_body_f32(const float* __restrict__ X,
                                            const float* __restrict__ W,
                                            const float* __restrict__ a_s,
                                            const float* __restrict__ a_d,
                                            __half* __restrict__ H,
                                            float* __restrict__ AS,
                                            float* __restrict__ AD, int n,
                                            int wave0, int nwaves, int lane) {
    int head = lane >> 4;
    float w[FIN];
#pragma unroll
    for (int k = 0; k < FIN; ++k) w[k] = W[k * 64 + lane];
    float asl = a_s[lane], adl = a_d[lane];

    for (int i = wave0; i < n; i += nwaves) {
        const float* __restrict__ xr = X + (size_t)i * FIN;  // uniform address
        float acc = 0.0f;
#pragma unroll
        for (int k = 0; k < FIN; ++k) acc += xr[k] * w[k];
        H[(size_t)i * 64 + lane] = __float2half_rn(acc);
        float s1 = acc * asl, s2 = acc * adl;
#pragma unroll
        for (int off = 1; off < 16; off <<= 1) {
            s1 += __shfl_xor(s1, off);
            s2 += __shfl_xor(s2, off);
        }
        if ((lane & 15) == 0) {
            AS[(size_t)i * 4 + head] = s1;
            AD[(size_t)i * 4 + head] = s2;
        }
    }
}

template <int FIN>
__global__ void node_linear3(const float* __restrict__ X,
                             const float* __restrict__ W,
                             const float* __restrict__ a_s,
                             const float* __restrict__ a_d,
                             __half* __restrict__ H,
                             float* __restrict__ AS,
                             float* __restrict__ AD, int n) {
    int lane = threadIdx.x & 63;
    int wave = __builtin_amdgcn_readfirstlane(
        (int)((blockIdx.x * blockDim.x + threadIdx.x) >> 6));
    int nwaves = (gridDim.x * blockDim.x) >> 6;
    nl_body_f32<FIN>(X, W, a_s, a_d, H, AS, AD, n, wave, nwaves, lane);
}

// fp16-input variant: rows read as wave-uniform UINT loads (s_load-able),
// unpacked to fp32. Keeps the scalar path AND the halved bytes.
template <int FIN>
__global__ void node_linear3h(const unsigned* __restrict__ X,  // [n, FIN/2] u32
                              const float* __restrict__ W,
                              const float* __restrict__ a_s,
                              const float* __restrict__ a_d,
                              __half* __restrict__ H,
                              float* __restrict__ AS,
                              float* __restrict__ AD, int n) {
    int lane = threadIdx.x & 63;
    int head = lane >> 4;
    int wave = __builtin_amdgcn_readfirstlane(
        (int)((blockIdx.x * blockDim.x + threadIdx.x) >> 6));
    int nwaves = (gridDim.x * blockDim.x) >> 6;

    float w[FIN];
#pragma unroll
    for (int k = 0; k < FIN; ++k) w[k] = W[k * 64 + lane];
    float asl = a_s[lane], adl = a_d[lane];

    for (int i = wave; i < n; i += nwaves) {
        const unsigned* __restrict__ xr = X + (size_t)i * (FIN / 2);  // uniform
        float acc = 0.0f;
#pragma unroll
        for (int k = 0; k < FIN / 2; ++k) {
            unsigned u = xr[k];
            __half2 hh = *reinterpret_cast<const __half2*>(&u);
            float2 f = __half22float2(hh);
            acc += f.x * w[2 * k] + f.y * w[2 * k + 1];
        }
        H[(size_t)i * 64 + lane] = __float2half_rn(acc);
        float s1 = acc * asl, s2 = acc * adl;
#pragma unroll
        for (int off = 1; off < 16; off <<= 1) {
            s1 += __shfl_xor(s1, off);
            s2 += __shfl_xor(s2, off);
        }
        if ((lane & 15) == 0) {
            AS[(size_t)i * 4 + head] = s1;
            AD[(size_t)i * 4 + head] = s2;
        }
    }
}

// ---------------------------------------------------------------------------
// FUSED: bucket_scatter (blocks [0,SCAT_BLOCKS)) + layer-1 node_linear
// (blocks [SCAT_BLOCKS, SCAT_BLOCKS+NL1_BLOCKS)). Independent work; the
// VALU-heavy nl1 hides inside the latency-bound scatter.
// pairs[bkt*BCAP + r] = src | (dst_local << 20)
// ---------------------------------------------------------------------------
__global__ void scatter_nl1(const int* __restrict__ src,
                            const int* __restrict__ dst,
                            int* __restrict__ bucketCnt,
                            unsigned int* __restrict__ pairs, int ne,
                            const float* __restrict__ X,
                            const float* __restrict__ W,
                            const float* __restrict__ a_s,
                            const float* __restrict__ a_d,
                            __half* __restrict__ H,
                            float* __restrict__ AS,
                            float* __restrict__ AD, int n) {
    __shared__ int hist[NBKT];
    __shared__ int base[NBKT];
    int tid = threadIdx.x;

    if (blockIdx.x >= SCAT_BLOCKS) {
        // ---- node_linear part ----
        int lane = tid & 63;
        int wave = __builtin_amdgcn_readfirstlane(
            (int)(((blockIdx.x - SCAT_BLOCKS) * blockDim.x + tid) >> 6));
        int nwaves = (NL1_BLOCKS * 256) >> 6;
        nl_body_f32<16>(X, W, a_s, a_d, H, AS, AD, n, wave, nwaves, lane);
        return;
    }

    // ---- scatter part ----
    for (int i = tid; i < NBKT; i += 256) hist[i] = 0;
    __syncthreads();

    int chunk = (ne + SCAT_BLOCKS - 1) / SCAT_BLOCKS;
    int beg = blockIdx.x * chunk;
    int end = min(beg + chunk, ne);

    for (int e = beg + tid; e < end; e += 256)
        atomicAdd(&hist[dst[e] >> BKT_SHIFT], 1);
    __syncthreads();

    for (int i = tid; i < NBKT; i += 256) {
        int h = hist[i];
        base[i] = h ? atomicAdd(&bucketCnt[i], h) : 0;  // reserve range
        hist[i] = 0;                                    // reuse as cursor
    }
    __syncthreads();

    for (int e = beg + tid; e < end; e += 256) {
        int d = dst[e];
        int bkt = d >> BKT_SHIFT;
        int r = base[bkt] + atomicAdd(&hist[bkt], 1);
        if (r < BCAP)
            pairs[(size_t)bkt * BCAP + r] =
                (unsigned)src[e] | ((unsigned)(d & (NPB - 1)) << 20);
    }
}

// one block: exclusive scan of bucket counts
__global__ void bucket_scan(const int* __restrict__ bucketCnt,
                            int* __restrict__ bucketOff,
                            int* __restrict__ indptr, int n) {
    __shared__ int sd[1024];
    int t = threadIdx.x;
    int v = (t < NBKT) ? min(bucketCnt[t], BCAP) : 0;
    sd[t] = v;
    __syncthreads();
    for (int off = 1; off < 1024; off <<= 1) {
        int x = (t >= off) ? sd[t - off] : 0;
        __syncthreads();
        if (t >= off) sd[t] += x;
        __syncthreads();
    }
    if (t < NBKT) bucketOff[t] = sd[t] - v;
    if (t == NBKT - 1) {
        bucketOff[NBKT] = sd[t];
        indptr[n] = sd[t];
    }
}

// one block per bucket: local counting sort in LDS, coalesced output
__global__ void bucket_sort(const unsigned int* __restrict__ pairs,
                            const int* __restrict__ bucketCnt,
                            const int* __restrict__ bucketOff,
                            int* __restrict__ srcs,
                            int* __restrict__ indptr, int n) {
    __shared__ int hist[NPB];
    __shared__ int offl[NPB];
    __shared__ int cur[NPB];
    __shared__ int lsrc[BCAP];
    int bkt = blockIdx.x;
    int t = threadIdx.x;
    int cnt = min(bucketCnt[bkt], BCAP);
    int boff = bucketOff[bkt];
    if (t < NPB) hist[t] = 0;
    __syncthreads();

    const unsigned int* __restrict__ p = pairs + (size_t)bkt * BCAP;
    unsigned int v[BCAP / 256];
#pragma unroll
    for (int i = 0; i < BCAP / 256; ++i) {
        int e = i * 256 + t;
        v[i] = 0u;
        if (e < cnt) {
            v[i] = p[e];
            atomicAdd(&hist[v[i] >> 20], 1);
        }
    }
    __syncthreads();
    if (t < NPB) offl[t] = hist[t];
    __syncthreads();
    for (int off = 1; off < NPB; off <<= 1) {
        int x = 0;
        if (t < NPB && t >= off) x = offl[t - off];
        __syncthreads();
        if (t < NPB && t >= off) offl[t] += x;
        __syncthreads();
    }
    if (t < NPB) {
        int ex = offl[t] - hist[t];   // exclusive
        cur[t] = ex;
        int node = bkt * NPB + t;
        if (node < n) indptr[node] = boff + ex;
    }
    __syncthreads();
#pragma unroll
    for (int i = 0; i < BCAP / 256; ++i) {
        int e = i * 256 + t;
        if (e < cnt) {
            int r = atomicAdd(&cur[v[i] >> 20], 1);
            lsrc[r] = (int)(v[i] & 0xFFFFFu);
        }
    }
    __syncthreads();
    for (int e = t; e < cnt; e += 256) srcs[boff + e] = lsrc[e];
}

// ---------------------------------------------------------------------------
// Pull-mode GAT aggregate v3: 4 dst nodes per wave, 16-lane group per node.
// Inner loop 4-wide (proven r8 config). NO atomics.
// MODE 0: concat+elu -> half [n,64]; MODE 1: head-mean+elu -> float [n,16];
// MODE 2: head-mean -> float [n,16]
// ---------------------------------------------------------------------------
template <int MODE, typename TOUT>
__global__ void gat_pull3(const __half* __restrict__ H,
                          const float* __restrict__ AS,
                          const float* __restrict__ AD,
                          const int* __restrict__ indptr,
                          const int* __restrict__ srcs,
                          const float* __restrict__ bias,
                          TOUT* __restrict__ out, int n) {
    int lane = threadIdx.x & 63;
    int grp  = lane >> 4;          // which node of the quad
    int sl   = lane & 15;          // channel-quad index (channels 4sl..4sl+3)
    int head = sl >> 2;            // head of this channel quad
    int wave = (blockIdx.x * blockDim.x + threadIdx.x) >> 6;
    int nwaves = (gridDim.x * blockDim.x) >> 6;

    for (int d0 = wave * 4; d0 < n; d0 += nwaves * 4) {
        int d = d0 + grp;
        if (d < n) {
            float ad  = AD[(size_t)d * 4 + head];
            float asd = AS[(size_t)d * 4 + head];
            // self-loop
            float t0 = asd + ad;
            float wself = __expf(t0 > 0.f ? t0 : 0.2f * t0);
            float den = wself;
            float4 h4s = loadH4(H + (size_t)d * 64 + sl * 4);
            float4 acc = {wself * h4s.x, wself * h4s.y,
                          wself * h4s.z, wself * h4s.w};

            int beg = indptr[d], end = indptr[d + 1];
            for (int e0 = beg; e0 < end; e0 += 16) {
                int cnt = min(16, end - e0);
                int myS = (sl < cnt) ? srcs[e0 + sl] : 0;  // 16/group, coalesced
                int j = 0;
                for (; j + 4 <= cnt; j += 4) {             // 4 gathers in flight
                    int s[4]; float a[4]; float4 h4[4];
#pragma unroll
                    for (int q = 0; q < 4; ++q)
                        s[q] = __shfl(myS, (grp << 4) + j + q);
#pragma unroll
                    for (int q = 0; q < 4; ++q)
                        a[q] = AS[(size_t)s[q] * 4 + head];
#pragma unroll
                    for (int q = 0; q < 4; ++q)
                        h4[q] = loadH4(H + (size_t)s[q] * 64 + sl * 4);
#pragma unroll
                    for (int q = 0; q < 4; ++q) {
                        float t = a[q] + ad;
                        float w = __expf(t > 0.f ? t : 0.2f * t);
                        den += w;
                        acc.x += w * h4[q].x; acc.y += w * h4[q].y;
                        acc.z += w * h4[q].z; acc.w += w * h4[q].w;
                    }
                }
                for (; j < cnt; ++j) {                     // tail
                    int s = __shfl(myS, (grp << 4) + j);
                    float t = AS[(size_t)s * 4 + head] + ad;
                    float w = __expf(t > 0.f ? t : 0.2f * t);
                    den += w;
                    float4 h4 = loadH4(H + (size_t)s * 64 + sl * 4);
                    acc.x += w * h4.x; acc.y += w * h4.y;
                    acc.z += w * h4.z; acc.w += w * h4.w;
                }
            }
            float inv = 1.0f / (den + 1e-16f);
            float4 v = {acc.x * inv, acc.y * inv, acc.z * inv, acc.w * inv};
            if (MODE == 0) {
                float4 b4 = *(const float4*)(bias + sl * 4);
                v.x += b4.x; v.y += b4.y; v.z += b4.z; v.w += b4.w;
                v.x = v.x > 0.f ? v.x : __expf(v.x) - 1.f;
                v.y = v.y > 0.f ? v.y : __expf(v.y) - 1.f;
                v.z = v.z > 0.f ? v.z : __expf(v.z) - 1.f;
                v.w = v.w > 0.f ? v.w : __expf(v.w) - 1.f;
                storeH4((__half*)out + (size_t)d * 64 + sl * 4, v);
            } else {
                // head-mean within group: offsets 4,8 fold the 4 heads
#pragma unroll
                for (int off = 4; off <= 8; off <<= 1) {
                    v.x += __shfl_xor(v.x, off);
                    v.y += __shfl_xor(v.y, off);
                    v.z += __shfl_xor(v.z, off);
                    v.w += __shfl_xor(v.w, off);
                }
                float4 b4 = *(const float4*)(bias + (sl & 3) * 4);
                v.x = 0.25f * v.x + b4.x; v.y = 0.25f * v.y + b4.y;
                v.z = 0.25f * v.z + b4.z; v.w = 0.25f * v.w + b4.w;
                if (MODE == 1) {
                    v.x = v.x > 0.f ? v.x : __expf(v.x) - 1.f;
                    v.y = v.y > 0.f ? v.y : __expf(v.y) - 1.f;
                    v.z = v.z > 0.f ? v.z : __expf(v.z) - 1.f;
                    v.w = v.w > 0.f ? v.w : __expf(v.w) - 1.f;
                }
                if (sl < 4)
                    *(float4*)((float*)out + (size_t)d * 16 + sl * 4) = v;
            }
        }
    }
}

// ---------------------------------------------------------------------------
// Two-stage mean-pool (no global atomics)
// ---------------------------------------------------------------------------
__global__ void pool_stage1(const float* __restrict__ Hf,
                            const int* __restrict__ batch,
                            float* __restrict__ partials, int n) {
    __shared__ float lp[POOL_SLOTS];
    int tid = threadIdx.x;
    for (int i = tid; i < POOL_SLOTS; i += 256) lp[i] = 0.0f;
    __syncthreads();

    int chunk = (n + POOL_BLOCKS - 1) / POOL_BLOCKS;
    int start = blockIdx.x * chunk;
    int end = min(start + chunk, n);
    int c = tid & 15;
    for (int node = start + (tid >> 4); node < end; node += 16) {
        int b = batch[node];
        atomicAdd(&lp[b * 16 + c], Hf[(size_t)node * 16 + c]);
        if (c == 0) atomicAdd(&lp[NB * NG + b], 1.0f);
    }
    __syncthreads();
    float* outp = partials + (size_t)blockIdx.x * POOL_SLOTS;
    for (int i = tid; i < POOL_SLOTS; i += 256) outp[i] = lp[i];
}

__global__ void pool_stage2(const float* __restrict__ partials,
                            float* __restrict__ pooled_counts) {
    int idx = blockIdx.x * blockDim.x + threadIdx.x;
    if (idx >= POOL_SLOTS) return;
    float s = 0.0f;
    for (int j = 0; j < POOL_BLOCKS; ++j)
        s += partials[(size_t)j * POOL_SLOTS + idx];
    pooled_counts[idx] = s;
}

// final MLP head, one thread per graph (64 graphs)
__global__ void mlp_head(const float* __restrict__ pooled_counts,
                         const float* __restrict__ stats,
                         const float* __restrict__ fw1, const float* __restrict__ fb1,
                         const float* __restrict__ fw2, const float* __restrict__ fb2,
                         const float* __restrict__ fw3, const float* __restrict__ fb3,
                         float* __restrict__ out) {
    int g = threadIdx.x;
    if (g >= NB) return;
    const float* pooled = pooled_counts;
    const float* counts = pooled_counts + NB * NG;
    float z[32];
    float inv = 1.0f / fmaxf(counts[g], 1.0f);
#pragma unroll
    for (int c = 0; c < 16; ++c) z[c] = pooled[g * 16 + c] * inv;
#pragma unroll
    for (int c = 0; c < 16; ++c) z[16 + c] = stats[g * 16 + c];

    float z1[32];
#pragma unroll
    for (int j = 0; j < 32; ++j) {
        float acc = fb1[j];
        for (int k = 0; k < 32; ++k) acc += z[k] * fw1[k * 32 + j];
        z1[j] = fmaxf(acc, 0.0f);
    }
    float z2[16];
#pragma unroll
    for (int j = 0; j < 16; ++j) {
        float acc = fb2[j];
        for (int k = 0; k < 32; ++k) acc += z1[k] * fw2[k * 16 + j];
        z2[j] = fmaxf(acc, 0.0f);
    }
    float acc = fb3[0];
#pragma unroll
    for (int k = 0; k < 16; ++k) acc += z2[k] * fw3[k];
    out[g] = acc;
}

extern "C" void kernel_launch(void* const* d_in, const int* in_sizes, int n_in,
                              void* d_out, int out_size, void* d_ws, size_t ws_size,
                              hipStream_t stream) {
    const float* x    = (const float*)d_in[0];
    const float* stats= (const float*)d_in[1];
    const float* W1   = (const float*)d_in[2];
    const float* a1s  = (const float*)d_in[3];
    const float* a1d  = (const float*)d_in[4];
    const float* b1   = (const float*)d_in[5];
    const float* W2   = (const float*)d_in[6];
    const float* a2s  = (const float*)d_in[7];
    const float* a2d  = (const float*)d_in[8];
    const float* b2   = (const float*)d_in[9];
    const float* W3   = (const float*)d_in[10];
    const float* a3s  = (const float*)d_in[11];
    const float* a3d  = (const float*)d_in[12];
    const float* b3   = (const float*)d_in[13];
    const float* fw1  = (const float*)d_in[14];
    const float* fb1  = (const float*)d_in[15];
    const float* fw2  = (const float*)d_in[16];
    const float* fb2  = (const float*)d_in[17];
    const float* fw3  = (const float*)d_in[18];
    const float* fb3  = (const float*)d_in[19];
    const int* ei     = (const int*)d_in[20];
    const int* batch  = (const int*)d_in[21];

    const int n = NNODES, ne = NEDGES;
    const int* srcI = ei;
    const int* dstI = ei + ne;

    // ---- workspace layout ----
    float* ws = (float*)d_ws;
    __half* Hh  = (__half*)ws;                       // [n,64] fp16 = 12.8MB
    float* B    = (float*)(Hh + (size_t)n * 64);     // 25.6MB region; pairs aliases
    __half* B16 = (__half*)B;                        // layer1 out fp16 [n,64]
    float* C2   = B + (size_t)n * 64;                // [n,16]
    float* AS   = C2 + (size_t)n * 16;               // [n,4]
    float* AD   = AS + (size_t)n * 4;                // [n,4]
    float* PC   = AD + (size_t)n * 4;                // pooled_counts [1088]
    float* PART = PC + POOL_SLOTS;                   // [128][1088]
    int* bucketCnt = (int*)(PART + (size_t)POOL_BLOCKS * POOL_SLOTS); // [NBKT]
    int* bucketOff = bucketCnt + NBKT;               // [NBKT+1]
    int* indptr    = bucketOff + NBKT + 1;           // [n+1]
    int* srcs      = indptr + n + 1;                 // [ne]
    unsigned int* pairs = (unsigned int*)B;          // 12.82MB, dead before layer 1

    const int TB = 256;
    const int nlBlocks   = 2048;
    const int pullBlocks = (n + 15) / 16;            // 4 waves/blk × 4 nodes/wave

    // ---- fused: CSR bucket scatter + layer-1 node_linear ----
    hipMemsetAsync(bucketCnt, 0, NBKT * sizeof(int), stream);
    scatter_nl1<<<SCAT_BLOCKS + NL1_BLOCKS, TB, 0, stream>>>(
        srcI, dstI, bucketCnt, pairs, ne,
        x, W1, a1s, a1d, Hh, AS, AD, n);
    bucket_scan<<<1, 1024, 0, stream>>>(bucketCnt, bucketOff, indptr, n);
    bucket_sort<<<NBKT, TB, 0, stream>>>(pairs, bucketCnt, bucketOff, srcs,
                                         indptr, n);

    // ---- layer 1 aggregate: 16 -> 4x16 concat, elu (fp16 out) ----
    gat_pull3<0, __half><<<pullBlocks, TB, 0, stream>>>(Hh, AS, AD, indptr, srcs, b1, B16, n);

    // ---- layer 2: 64 (fp16 in, scalar u32 loads) -> head-mean 16, elu ----
    node_linear3h<64><<<nlBlocks, TB, 0, stream>>>((const unsigned*)B16, W2, a2s, a2d, Hh, AS, AD, n);
    gat_pull3<1, float><<<pullBlocks, TB, 0, stream>>>(Hh, AS, AD, indptr, srcs, b2, C2, n);

    // ---- layer 3: 16 -> head-mean 16, no act ----
    node_linear3<16><<<nlBlocks, TB, 0, stream>>>(C2, W3, a3s, a3d, Hh, AS, AD, n);
    gat_pull3<2, float><<<pullBlocks, TB, 0, stream>>>(Hh, AS, AD, indptr, srcs, b3, B, n);

    // ---- two-stage pool + MLP ----
    pool_stage1<<<POOL_BLOCKS, TB, 0, stream>>>(B, batch, PART, n);
    pool_stage2<<<(POOL_SLOTS + TB - 1) / TB, TB, 0, stream>>>(PART, PC);
    mlp_head<<<1, 64, 0, stream>>>(PC, stats, fw1, fb1, fw2, fb2, fw3, fb3,
                                   (float*)d_out);
}

// Round 11
// 337.261 us; speedup vs baseline: 1.2184x; 1.0552x over previous
//
#include <hip/hip_runtime.h>
#include <hip/hip_bf16.h>
#include <hip/hip_fp16.h>

#define NNODES 100000
#define NEDGES 1600000
#define NHEADS 4
#define NHID   16
#define NB     64
#define NG     16
#define POOL_BLOCKS 256
#define POOL_SLOTS (NB * NG + NB)   // 1088: [64x16 pooled | 64 counts]

// CSR counting-sort parameters
#define BKT_SHIFT 7
#define NPB 128                               // nodes per bucket
#define NBKT ((NNODES + NPB - 1) / NPB)       // 782
#define BCAP 4096                             // per-bucket capacity (mean ~2046)
#define SCAT_BLOCKS 256                       // 1/CU; ILP-4 supplies latency hiding
#define NL1_BLOCKS 2048

__device__ __forceinline__ float leaky02(float v) {
    return v > 0.0f ? v : 0.2f * v;
}

// load 4 consecutive halves as float4 (8-byte aligned)
__device__ __forceinline__ float4 loadH4(const __half* p) {
    uint2 raw = *(const uint2*)p;
    __half2 a = *reinterpret_cast<const __half2*>(&raw.x);
    __half2 b = *reinterpret_cast<const __half2*>(&raw.y);
    float2 fa = __half22float2(a), fb = __half22float2(b);
    return make_float4(fa.x, fa.y, fb.x, fb.y);
}

__device__ __forceinline__ void storeH4(__half* p, float4 v) {
    __half2 a = __floats2half2_rn(v.x, v.y);
    __half2 b = __floats2half2_rn(v.z, v.w);
    uint2 raw;
    raw.x = *reinterpret_cast<unsigned*>(&a);
    raw.y = *reinterpret_cast<unsigned*>(&b);
    *(uint2*)p = raw;
}

// ---------------------------------------------------------------------------
// node_linear device bodies: wave-per-node, lane = output channel (h*16+c).
// Node index wave-uniform (readfirstlane) -> x row via SCALAR loads.
// ---------------------------------------------------------------------------
template <int FIN>
__device__ __forceinline__ void nl_body_f32(const float* __restrict__ X,
                                            const float* __restrict__ W,
                                            const float* __restrict__ a_s,
                                            const float* __restrict__ a_d,
                                            __half* __restrict__ H,
                                            float* __restrict__ AS,
                                            float* __restrict__ AD, int n,
                                            int wave0, int nwaves, int lane) {
    int head = lane >> 4;
    float w[FIN];
#pragma unroll
    for (int k = 0; k < FIN; ++k) w[k] = W[k * 64 + lane];
    float asl = a_s[lane], adl = a_d[lane];

    for (int i = wave0; i < n; i += nwaves) {
        const float* __restrict__ xr = X + (size_t)i * FIN;  // uniform address
        float acc = 0.0f;
#pragma unroll
        for (int k = 0; k < FIN; ++k) acc += xr[k] * w[k];
        H[(size_t)i * 64 + lane] = __float2half_rn(acc);
        float s1 = acc * asl, s2 = acc * adl;
#pragma unroll
        for (int off = 1; off < 16; off <<= 1) {
            s1 += __shfl_xor(s1, off);
            s2 += __shfl_xor(s2, off);
        }
        if ((lane & 15) == 0) {
            AS[(size_t)i * 4 + head] = s1;
            AD[(size_t)i * 4 + head] = s2;
        }
    }
}

template <int FIN>
__global__ void node_linear3(const float* __restrict__ X,
                             const float* __restrict__ W,
                             const float* __restrict__ a_s,
                             const float* __restrict__ a_d,
                             __half* __restrict__ H,
                             float* __restrict__ AS,
                             float* __restrict__ AD, int n) {
    int lane = threadIdx.x & 63;
    int wave = __builtin_amdgcn_readfirstlane(
        (int)((blockIdx.x * blockDim.x + threadIdx.x) >> 6));
    int nwaves = (gridDim.x * blockDim.x) >> 6;
    nl_body_f32<FIN>(X, W, a_s, a_d, H, AS, AD, n, wave, nwaves, lane);
}

// fp16-input variant: rows read as wave-uniform UINT loads (s_load-able),
// unpacked to fp32. Keeps the scalar path AND the halved bytes.
template <int FIN>
__global__ void node_linear3h(const unsigned* __restrict__ X,  // [n, FIN/2] u32
                              const float* __restrict__ W,
                              const float* __restrict__ a_s,
                              const float* __restrict__ a_d,
                              __half* __restrict__ H,
                              float* __restrict__ AS,
                              float* __restrict__ AD, int n) {
    int lane = threadIdx.x & 63;
    int head = lane >> 4;
    int wave = __builtin_amdgcn_readfirstlane(
        (int)((blockIdx.x * blockDim.x + threadIdx.x) >> 6));
    int nwaves = (gridDim.x * blockDim.x) >> 6;

    float w[FIN];
#pragma unroll
    for (int k = 0; k < FIN; ++k) w[k] = W[k * 64 + lane];
    float asl = a_s[lane], adl = a_d[lane];

    for (int i = wave; i < n; i += nwaves) {
        const unsigned* __restrict__ xr = X + (size_t)i * (FIN / 2);  // uniform
        float acc = 0.0f;
#pragma unroll
        for (int k = 0; k < FIN / 2; ++k) {
            unsigned u = xr[k];
            __half2 hh = *reinterpret_cast<const __half2*>(&u);
            float2 f = __half22float2(hh);
            acc += f.x * w[2 * k] + f.y * w[2 * k + 1];
        }
        H[(size_t)i * 64 + lane] = __float2half_rn(acc);
        float s1 = acc * asl, s2 = acc * adl;
#pragma unroll
        for (int off = 1; off < 16; off <<= 1) {
            s1 += __shfl_xor(s1, off);
            s2 += __shfl_xor(s2, off);
        }
        if ((lane & 15) == 0) {
            AS[(size_t)i * 4 + head] = s1;
            AD[(size_t)i * 4 + head] = s2;
        }
    }
}

// ---------------------------------------------------------------------------
// FUSED: bucket_scatter (blocks [0,SCAT_BLOCKS)) + layer-1 node_linear.
// Scatter phases use 4-deep ILP batching: 4 loads / 4 LDS atomics / 4 stores
// in flight per thread. pairs[bkt*BCAP + r] = src | (dst_local << 20)
// ---------------------------------------------------------------------------
__global__ void scatter_nl1(const int* __restrict__ src,
                            const int* __restrict__ dst,
                            int* __restrict__ bucketCnt,
                            unsigned int* __restrict__ pairs, int ne,
                            const float* __restrict__ X,
                            const float* __restrict__ W,
                            const float* __restrict__ a_s,
                            const float* __restrict__ a_d,
                            __half* __restrict__ H,
                            float* __restrict__ AS,
                            float* __restrict__ AD, int n) {
    __shared__ int hist[NBKT];
    __shared__ int base[NBKT];
    int tid = threadIdx.x;

    if (blockIdx.x >= SCAT_BLOCKS) {
        // ---- node_linear part ----
        int lane = tid & 63;
        int wave = __builtin_amdgcn_readfirstlane(
            (int)(((blockIdx.x - SCAT_BLOCKS) * blockDim.x + tid) >> 6));
        int nwaves = (NL1_BLOCKS * 256) >> 6;
        nl_body_f32<16>(X, W, a_s, a_d, H, AS, AD, n, wave, nwaves, lane);
        return;
    }

    // ---- scatter part ----
    for (int i = tid; i < NBKT; i += 256) hist[i] = 0;
    __syncthreads();

    int chunk = (ne + SCAT_BLOCKS - 1) / SCAT_BLOCKS;
    int beg = blockIdx.x * chunk;
    int end = min(beg + chunk, ne);

    // phase 1: histogram, 4 coalesced loads in flight
    for (int e0 = beg; e0 < end; e0 += 1024) {
        int d[4];
#pragma unroll
        for (int q = 0; q < 4; ++q) {
            int e = e0 + q * 256 + tid;
            d[q] = (e < end) ? dst[e] : -1;
        }
#pragma unroll
        for (int q = 0; q < 4; ++q)
            if (d[q] >= 0) atomicAdd(&hist[d[q] >> BKT_SHIFT], 1);
    }
    __syncthreads();

    for (int i = tid; i < NBKT; i += 256) {
        int h = hist[i];
        base[i] = h ? atomicAdd(&bucketCnt[i], h) : 0;  // reserve range
        hist[i] = 0;                                    // reuse as cursor
    }
    __syncthreads();

    // phase 3: scatter, 4 edges batched (4 stores in flight)
    for (int e0 = beg; e0 < end; e0 += 1024) {
        int d[4], s[4];
#pragma unroll
        for (int q = 0; q < 4; ++q) {
            int e = e0 + q * 256 + tid;
            d[q] = (e < end) ? dst[e] : -1;
            s[q] = (e < end) ? src[e] : 0;
        }
        int r[4], bkt[4];
#pragma unroll
        for (int q = 0; q < 4; ++q) {
            if (d[q] >= 0) {
                bkt[q] = d[q] >> BKT_SHIFT;
                r[q] = base[bkt[q]] + atomicAdd(&hist[bkt[q]], 1);
            }
        }
#pragma unroll
        for (int q = 0; q < 4; ++q) {
            if (d[q] >= 0 && r[q] < BCAP)
                pairs[(size_t)bkt[q] * BCAP + r[q]] =
                    (unsigned)s[q] | ((unsigned)(d[q] & (NPB - 1)) << 20);
        }
    }
}

// ---------------------------------------------------------------------------
// bucket_sort with inline offset computation (bucket_scan folded in):
// each block reduces min(bucketCnt[j],BCAP) for j<bkt to get its offset.
// ---------------------------------------------------------------------------
__global__ void bucket_sort(const unsigned int* __restrict__ pairs,
                            const int* __restrict__ bucketCnt,
                            int* __restrict__ srcs,
                            int* __restrict__ indptr, int n) {
    __shared__ int hist[NPB];
    __shared__ int offl[NPB];
    __shared__ int cur[NPB];
    __shared__ int red[256];
    __shared__ int lsrc[BCAP];
    int bkt = blockIdx.x;
    int t = threadIdx.x;
    int cnt = min(bucketCnt[bkt], BCAP);

    // ---- compute global offset: sum of clamped counts of lower buckets ----
    int partial = 0;
    for (int j = t; j < bkt; j += 256) partial += min(bucketCnt[j], BCAP);
    red[t] = partial;
    if (t < NPB) hist[t] = 0;
    __syncthreads();
    for (int s = 128; s > 0; s >>= 1) {
        if (t < s) red[t] += red[t + s];
        __syncthreads();
    }
    int boff = red[0];
    if (bkt == NBKT - 1 && t == 0) indptr[n] = boff + cnt;

    const unsigned int* __restrict__ p = pairs + (size_t)bkt * BCAP;
    unsigned int v[BCAP / 256];
#pragma unroll
    for (int i = 0; i < BCAP / 256; ++i) {
        int e = i * 256 + t;
        v[i] = 0u;
        if (e < cnt) {
            v[i] = p[e];
            atomicAdd(&hist[v[i] >> 20], 1);
        }
    }
    __syncthreads();
    if (t < NPB) offl[t] = hist[t];
    __syncthreads();
    for (int off = 1; off < NPB; off <<= 1) {
        int x = 0;
        if (t < NPB && t >= off) x = offl[t - off];
        __syncthreads();
        if (t < NPB && t >= off) offl[t] += x;
        __syncthreads();
    }
    if (t < NPB) {
        int ex = offl[t] - hist[t];   // exclusive
        cur[t] = ex;
        int node = bkt * NPB + t;
        if (node < n) indptr[node] = boff + ex;
    }
    __syncthreads();
#pragma unroll
    for (int i = 0; i < BCAP / 256; ++i) {
        int e = i * 256 + t;
        if (e < cnt) {
            int r = atomicAdd(&cur[v[i] >> 20], 1);
            lsrc[r] = (int)(v[i] & 0xFFFFFu);
        }
    }
    __syncthreads();
    for (int e = t; e < cnt; e += 256) srcs[boff + e] = lsrc[e];
}

// ---------------------------------------------------------------------------
// Pull-mode GAT aggregate v3: 4 dst nodes per wave, 16-lane group per node.
// Inner loop 4-wide. NO atomics.
// MODE 0: concat+elu -> half [n,64]; MODE 1: head-mean+elu -> float [n,16];
// MODE 2: head-mean -> float [n,16]
// ---------------------------------------------------------------------------
template <int MODE, typename TOUT>
__global__ void gat_pull3(const __half* __restrict__ H,
                          const float* __restrict__ AS,
                          const float* __restrict__ AD,
                          const int* __restrict__ indptr,
                          const int* __restrict__ srcs,
                          const float* __restrict__ bias,
                          TOUT* __restrict__ out, int n) {
    int lane = threadIdx.x & 63;
    int grp  = lane >> 4;          // which node of the quad
    int sl   = lane & 15;          // channel-quad index (channels 4sl..4sl+3)
    int head = sl >> 2;            // head of this channel quad
    int wave = (blockIdx.x * blockDim.x + threadIdx.x) >> 6;
    int nwaves = (gridDim.x * blockDim.x) >> 6;

    for (int d0 = wave * 4; d0 < n; d0 += nwaves * 4) {
        int d = d0 + grp;
        if (d < n) {
            float ad  = AD[(size_t)d * 4 + head];
            float asd = AS[(size_t)d * 4 + head];
            // self-loop
            float t0 = asd + ad;
            float wself = __expf(t0 > 0.f ? t0 : 0.2f * t0);
            float den = wself;
            float4 h4s = loadH4(H + (size_t)d * 64 + sl * 4);
            float4 acc = {wself * h4s.x, wself * h4s.y,
                          wself * h4s.z, wself * h4s.w};

            int beg = indptr[d], end = indptr[d + 1];
            for (int e0 = beg; e0 < end; e0 += 16) {
                int cnt = min(16, end - e0);
                int myS = (sl < cnt) ? srcs[e0 + sl] : 0;  // 16/group, coalesced
                int j = 0;
                for (; j + 4 <= cnt; j += 4) {             // 4 gathers in flight
                    int s[4]; float a[4]; float4 h4[4];
#pragma unroll
                    for (int q = 0; q < 4; ++q)
                        s[q] = __shfl(myS, (grp << 4) + j + q);
#pragma unroll
                    for (int q = 0; q < 4; ++q)
                        a[q] = AS[(size_t)s[q] * 4 + head];
#pragma unroll
                    for (int q = 0; q < 4; ++q)
                        h4[q] = loadH4(H + (size_t)s[q] * 64 + sl * 4);
#pragma unroll
                    for (int q = 0; q < 4; ++q) {
                        float t = a[q] + ad;
                        float w = __expf(t > 0.f ? t : 0.2f * t);
                        den += w;
                        acc.x += w * h4[q].x; acc.y += w * h4[q].y;
                        acc.z += w * h4[q].z; acc.w += w * h4[q].w;
                    }
                }
                for (; j < cnt; ++j) {                     // tail
                    int s = __shfl(myS, (grp << 4) + j);
                    float t = AS[(size_t)s * 4 + head] + ad;
                    float w = __expf(t > 0.f ? t : 0.2f * t);
                    den += w;
                    float4 h4 = loadH4(H + (size_t)s * 64 + sl * 4);
                    acc.x += w * h4.x; acc.y += w * h4.y;
                    acc.z += w * h4.z; acc.w += w * h4.w;
                }
            }
            float inv = 1.0f / (den + 1e-16f);
            float4 v = {acc.x * inv, acc.y * inv, acc.z * inv, acc.w * inv};
            if (MODE == 0) {
                float4 b4 = *(const float4*)(bias + sl * 4);
                v.x += b4.x; v.y += b4.y; v.z += b4.z; v.w += b4.w;
                v.x = v.x > 0.f ? v.x : __expf(v.x) - 1.f;
                v.y = v.y > 0.f ? v.y : __expf(v.y) - 1.f;
                v.z = v.z > 0.f ? v.z : __expf(v.z) - 1.f;
                v.w = v.w > 0.f ? v.w : __expf(v.w) - 1.f;
                storeH4((__half*)out + (size_t)d * 64 + sl * 4, v);
            } else {
                // head-mean within group: offsets 4,8 fold the 4 heads
#pragma unroll
                for (int off = 4; off <= 8; off <<= 1) {
                    v.x += __shfl_xor(v.x, off);
                    v.y += __shfl_xor(v.y, off);
                    v.z += __shfl_xor(v.z, off);
                    v.w += __shfl_xor(v.w, off);
                }
                float4 b4 = *(const float4*)(bias + (sl & 3) * 4);
                v.x = 0.25f * v.x + b4.x; v.y = 0.25f * v.y + b4.y;
                v.z = 0.25f * v.z + b4.z; v.w = 0.25f * v.w + b4.w;
                if (MODE == 1) {
                    v.x = v.x > 0.f ? v.x : __expf(v.x) - 1.f;
                    v.y = v.y > 0.f ? v.y : __expf(v.y) - 1.f;
                    v.z = v.z > 0.f ? v.z : __expf(v.z) - 1.f;
                    v.w = v.w > 0.f ? v.w : __expf(v.w) - 1.f;
                }
                if (sl < 4)
                    *(float4*)((float*)out + (size_t)d * 16 + sl * 4) = v;
            }
        }
    }
}

// ---------------------------------------------------------------------------
// Two-stage mean-pool (no global atomics)
// ---------------------------------------------------------------------------
__global__ void pool_stage1(const float* __restrict__ Hf,
                            const int* __restrict__ batch,
                            float* __restrict__ partials, int n) {
    __shared__ float lp[POOL_SLOTS];
    int tid = threadIdx.x;
    for (int i = tid; i < POOL_SLOTS; i += 256) lp[i] = 0.0f;
    __syncthreads();

    int chunk = (n + POOL_BLOCKS - 1) / POOL_BLOCKS;
    int start = blockIdx.x * chunk;
    int end = min(start + chunk, n);
    int c = tid & 15;
    for (int node = start + (tid >> 4); node < end; node += 16) {
        int b = batch[node];
        atomicAdd(&lp[b * 16 + c], Hf[(size_t)node * 16 + c]);
        if (c == 0) atomicAdd(&lp[NB * NG + b], 1.0f);
    }
    __syncthreads();
    float* outp = partials + (size_t)blockIdx.x * POOL_SLOTS;
    for (int i = tid; i < POOL_SLOTS; i += 256) outp[i] = lp[i];
}

__global__ void pool_stage2(const float* __restrict__ partials,
                            float* __restrict__ pooled_counts) {
    int idx = blockIdx.x * blockDim.x + threadIdx.x;
    if (idx >= POOL_SLOTS) return;
    float s = 0.0f;
    for (int j = 0; j < POOL_BLOCKS; ++j)
        s += partials[(size_t)j * POOL_SLOTS + idx];
    pooled_counts[idx] = s;
}

// final MLP head, one thread per graph (64 graphs)
__global__ void mlp_head(const float* __restrict__ pooled_counts,
                         const float* __restrict__ stats,
                         const float* __restrict__ fw1, const float* __restrict__ fb1,
                         const float* __restrict__ fw2, const float* __restrict__ fb2,
                         const float* __restrict__ fw3, const float* __restrict__ fb3,
                         float* __restrict__ out) {
    int g = threadIdx.x;
    if (g >= NB) return;
    const float* pooled = pooled_counts;
    const float* counts = pooled_counts + NB * NG;
    float z[32];
    float inv = 1.0f / fmaxf(counts[g], 1.0f);
#pragma unroll
    for (int c = 0; c < 16; ++c) z[c] = pooled[g * 16 + c] * inv;
#pragma unroll
    for (int c = 0; c < 16; ++c) z[16 + c] = stats[g * 16 + c];

    float z1[32];
#pragma unroll
    for (int j = 0; j < 32; ++j) {
        float acc = fb1[j];
        for (int k = 0; k < 32; ++k) acc += z[k] * fw1[k * 32 + j];
        z1[j] = fmaxf(acc, 0.0f);
    }
    float z2[16];
#pragma unroll
    for (int j = 0; j < 16; ++j) {
        float acc = fb2[j];
        for (int k = 0; k < 32; ++k) acc += z1[k] * fw2[k * 16 + j];
        z2[j] = fmaxf(acc, 0.0f);
    }
    float acc = fb3[0];
#pragma unroll
    for (int k = 0; k < 16; ++k) acc += z2[k] * fw3[k];
    out[g] = acc;
}

extern "C" void kernel_launch(void* const* d_in, const int* in_sizes, int n_in,
                              void* d_out, int out_size, void* d_ws, size_t ws_size,
                              hipStream_t stream) {
    const float* x    = (const float*)d_in[0];
    const float* stats= (const float*)d_in[1];
    const float* W1   = (const float*)d_in[2];
    const float* a1s  = (const float*)d_in[3];
    const float* a1d  = (const float*)d_in[4];
    const float* b1   = (const float*)d_in[5];
    const float* W2   = (const float*)d_in[6];
    const float* a2s  = (const float*)d_in[7];
    const float* a2d  = (const float*)d_in[8];
    const float* b2   = (const float*)d_in[9];
    const float* W3   = (const float*)d_in[10];
    const float* a3s  = (const float*)d_in[11];
    const float* a3d  = (const float*)d_in[12];
    const float* b3   = (const float*)d_in[13];
    const float* fw1  = (const float*)d_in[14];
    const float* fb1  = (const float*)d_in[15];
    const float* fw2  = (const float*)d_in[16];
    const float* fb2  = (const float*)d_in[17];
    const float* fw3  = (const float*)d_in[18];
    const float* fb3  = (const float*)d_in[19];
    const int* ei     = (const int*)d_in[20];
    const int* batch  = (const int*)d_in[21];

    const int n = NNODES, ne = NEDGES;
    const int* srcI = ei;
    const int* dstI = ei + ne;

    // ---- workspace layout ----
    float* ws = (float*)d_ws;
    __half* Hh  = (__half*)ws;                       // [n,64] fp16 = 12.8MB
    float* B    = (float*)(Hh + (size_t)n * 64);     // 25.6MB region; pairs aliases
    __half* B16 = (__half*)B;                        // layer1 out fp16 [n,64]
    float* C2   = B + (size_t)n * 64;                // [n,16]
    float* AS   = C2 + (size_t)n * 16;               // [n,4]
    float* AD   = AS + (size_t)n * 4;                // [n,4]
    float* PC   = AD + (size_t)n * 4;                // pooled_counts [1088]
    float* PART = PC + POOL_SLOTS;                   // [256][1088]
    int* bucketCnt = (int*)(PART + (size_t)POOL_BLOCKS * POOL_SLOTS); // [NBKT]
    int* indptr    = bucketCnt + NBKT;               // [n+1]
    int* srcs      = indptr + n + 1;                 // [ne]
    unsigned int* pairs = (unsigned int*)B;          // 12.82MB, dead before layer 1

    const int TB = 256;
    const int nlBlocks   = 2048;
    const int pullBlocks = (n + 15) / 16;            // 4 waves/blk × 4 nodes/wave

    // ---- fused: CSR bucket scatter + layer-1 node_linear ----
    hipMemsetAsync(bucketCnt, 0, NBKT * sizeof(int), stream);
    scatter_nl1<<<SCAT_BLOCKS + NL1_BLOCKS, TB, 0, stream>>>(
        srcI, dstI, bucketCnt, pairs, ne,
        x, W1, a1s, a1d, Hh, AS, AD, n);
    bucket_sort<<<NBKT, TB, 0, stream>>>(pairs, bucketCnt, srcs, indptr, n);

    // ---- layer 1 aggregate: 16 -> 4x16 concat, elu (fp16 out) ----
    gat_pull3<0, __half><<<pullBlocks, TB, 0, stream>>>(Hh, AS, AD, indptr, srcs, b1, B16, n);

    // ---- layer 2: 64 (fp16 in, scalar u32 loads) -> head-mean 16, elu ----
    node_linear3h<64><<<nlBlocks, TB, 0, stream>>>((const unsigned*)B16, W2, a2s, a2d, Hh, AS, AD, n);
    gat_pull3<1, float><<<pullBlocks, TB, 0, stream>>>(Hh, AS, AD, indptr, srcs, b2, C2, n);

    // ---- layer 3: 16 -> head-mean 16, no act ----
    node_linear3<16><<<nlBlocks, TB, 0, stream>>>(C2, W3, a3s, a3d, Hh, AS, AD, n);
    gat_pull3<2, float><<<pullBlocks, TB, 0, stream>>>(Hh, AS, AD, indptr, srcs, b3, B, n);

    // ---- two-stage pool + MLP ----
    pool_stage1<<<POOL_BLOCKS, TB, 0, stream>>>(B, batch, PART, n);
    pool_stage2<<<(POOL_SLOTS + TB - 1) / TB, TB, 0, stream>>>(PART, PC);
    mlp_head<<<1, 64, 0, stream>>>(PC, stats, fw1, fb1, fw2, fb2, fw3, fb3,
                                   (float*)d_out);
}

// Round 12
// 327.312 us; speedup vs baseline: 1.2555x; 1.0304x over previous
//
#include <hip/hip_runtime.h>
#include <hip/hip_bf16.h>
#include <hip/hip_fp16.h>

#define NNODES 100000
#define NEDGES 1600000
#define NHEADS 4
#define NHID   16
#define NB     64
#define NG     16
#define POOL_BLOCKS 256
#define POOL_SLOTS (NB * NG + NB)   // 1088: [64x16 pooled | 64 counts]

// CSR counting-sort parameters
#define BKT_SHIFT 7
#define NPB 128                               // nodes per bucket
#define NBKT ((NNODES + NPB - 1) / NPB)       // 782
#define BCAP 4096                             // per-bucket capacity (mean ~2046)
#define SCAT_BLOCKS 256                       // 1/CU; ILP-4 supplies latency hiding
#define NL1_BLOCKS 2048

typedef float vf2 __attribute__((ext_vector_type(2)));

__device__ __forceinline__ float leaky02(float v) {
    return v > 0.0f ? v : 0.2f * v;
}

// ---- fp8 (OCP e4m3, gfx950-native) helpers ----
__device__ __forceinline__ unsigned char cvt_fp8(float a) {
    int r = __builtin_amdgcn_cvt_pk_fp8_f32(a, a, 0, false);
    return (unsigned char)(r & 0xFF);
}

// load 4 consecutive fp8 as float4 (4-byte aligned) — 1 load + 2 pk-cvt
__device__ __forceinline__ float4 loadQ4(const unsigned char* p) {
    int u = *(const int*)p;
    vf2 lo = __builtin_amdgcn_cvt_pk_f32_fp8(u, false);
    vf2 hi = __builtin_amdgcn_cvt_pk_f32_fp8(u, true);
    return make_float4(lo.x, lo.y, hi.x, hi.y);
}

__device__ __forceinline__ void storeH4(__half* p, float4 v) {
    __half2 a = __floats2half2_rn(v.x, v.y);
    __half2 b = __floats2half2_rn(v.z, v.w);
    uint2 raw;
    raw.x = *reinterpret_cast<unsigned*>(&a);
    raw.y = *reinterpret_cast<unsigned*>(&b);
    *(uint2*)p = raw;
}

// ---------------------------------------------------------------------------
// node_linear device bodies: wave-per-node, lane = output channel (h*16+c).
// Node index wave-uniform (readfirstlane) -> x row via SCALAR loads.
// H stored fp8 e4m3 (gathered by the pull); AS/AD fp32.
// ---------------------------------------------------------------------------
template <int FIN>
__device__ __forceinline__ void nl_body_f32(const float* __restrict__ X,
                                            const float* __restrict__ W,
                                            const float* __restrict__ a_s,
                                            const float* __restrict__ a_d,
                                            unsigned char* __restrict__ H,
                                            float* __restrict__ AS,
                                            float* __restrict__ AD, int n,
                                            int wave0, int nwaves, int lane) {
    int head = lane >> 4;
    float w[FIN];
#pragma unroll
    for (int k = 0; k < FIN; ++k) w[k] = W[k * 64 + lane];
    float asl = a_s[lane], adl = a_d[lane];

    for (int i = wave0; i < n; i += nwaves) {
        const float* __restrict__ xr = X + (size_t)i * FIN;  // uniform address
        float acc = 0.0f;
#pragma unroll
        for (int k = 0; k < FIN; ++k) acc += xr[k] * w[k];
        H[(size_t)i * 64 + lane] = cvt_fp8(acc);
        float s1 = acc * asl, s2 = acc * adl;
#pragma unroll
        for (int off = 1; off < 16; off <<= 1) {
            s1 += __shfl_xor(s1, off);
            s2 += __shfl_xor(s2, off);
        }
        if ((lane & 15) == 0) {
            AS[(size_t)i * 4 + head] = s1;
            AD[(size_t)i * 4 + head] = s2;
        }
    }
}

template <int FIN>
__global__ void node_linear3(const float* __restrict__ X,
                             const float* __restrict__ W,
                             const float* __restrict__ a_s,
                             const float* __restrict__ a_d,
                             unsigned char* __restrict__ H,
                             float* __restrict__ AS,
                             float* __restrict__ AD, int n) {
    int lane = threadIdx.x & 63;
    int wave = __builtin_amdgcn_readfirstlane(
        (int)((blockIdx.x * blockDim.x + threadIdx.x) >> 6));
    int nwaves = (gridDim.x * blockDim.x) >> 6;
    nl_body_f32<FIN>(X, W, a_s, a_d, H, AS, AD, n, wave, nwaves, lane);
}

// fp16-input variant: rows read as wave-uniform UINT loads (s_load-able),
// unpacked to fp32. Keeps the scalar path AND the halved bytes.
template <int FIN>
__global__ void node_linear3h(const unsigned* __restrict__ X,  // [n, FIN/2] u32
                              const float* __restrict__ W,
                              const float* __restrict__ a_s,
                              const float* __restrict__ a_d,
                              unsigned char* __restrict__ H,
                              float* __restrict__ AS,
                              float* __restrict__ AD, int n) {
    int lane = threadIdx.x & 63;
    int head = lane >> 4;
    int wave = __builtin_amdgcn_readfirstlane(
        (int)((blockIdx.x * blockDim.x + threadIdx.x) >> 6));
    int nwaves = (gridDim.x * blockDim.x) >> 6;

    float w[FIN];
#pragma unroll
    for (int k = 0; k < FIN; ++k) w[k] = W[k * 64 + lane];
    float asl = a_s[lane], adl = a_d[lane];

    for (int i = wave; i < n; i += nwaves) {
        const unsigned* __restrict__ xr = X + (size_t)i * (FIN / 2);  // uniform
        float acc = 0.0f;
#pragma unroll
        for (int k = 0; k < FIN / 2; ++k) {
            unsigned u = xr[k];
            __half2 hh = *reinterpret_cast<const __half2*>(&u);
            float2 f = __half22float2(hh);
            acc += f.x * w[2 * k] + f.y * w[2 * k + 1];
        }
        H[(size_t)i * 64 + lane] = cvt_fp8(acc);
        float s1 = acc * asl, s2 = acc * adl;
#pragma unroll
        for (int off = 1; off < 16; off <<= 1) {
            s1 += __shfl_xor(s1, off);
            s2 += __shfl_xor(s2, off);
        }
        if ((lane & 15) == 0) {
            AS[(size_t)i * 4 + head] = s1;
            AD[(size_t)i * 4 + head] = s2;
        }
    }
}

// ---------------------------------------------------------------------------
// FUSED: bucket_scatter (blocks [0,SCAT_BLOCKS)) + layer-1 node_linear.
// Scatter phases use 4-deep ILP batching. pairs = src | (dst_local << 20)
// ---------------------------------------------------------------------------
__global__ void scatter_nl1(const int* __restrict__ src,
                            const int* __restrict__ dst,
                            int* __restrict__ bucketCnt,
                            unsigned int* __restrict__ pairs, int ne,
                            const float* __restrict__ X,
                            const float* __restrict__ W,
                            const float* __restrict__ a_s,
                            const float* __restrict__ a_d,
                            unsigned char* __restrict__ H,
                            float* __restrict__ AS,
                            float* __restrict__ AD, int n) {
    __shared__ int hist[NBKT];
    __shared__ int base[NBKT];
    int tid = threadIdx.x;

    if (blockIdx.x >= SCAT_BLOCKS) {
        // ---- node_linear part ----
        int lane = tid & 63;
        int wave = __builtin_amdgcn_readfirstlane(
            (int)(((blockIdx.x - SCAT_BLOCKS) * blockDim.x + tid) >> 6));
        int nwaves = (NL1_BLOCKS * 256) >> 6;
        nl_body_f32<16>(X, W, a_s, a_d, H, AS, AD, n, wave, nwaves, lane);
        return;
    }

    // ---- scatter part ----
    for (int i = tid; i < NBKT; i += 256) hist[i] = 0;
    __syncthreads();

    int chunk = (ne + SCAT_BLOCKS - 1) / SCAT_BLOCKS;
    int beg = blockIdx.x * chunk;
    int end = min(beg + chunk, ne);

    // phase 1: histogram, 4 coalesced loads in flight
    for (int e0 = beg; e0 < end; e0 += 1024) {
        int d[4];
#pragma unroll
        for (int q = 0; q < 4; ++q) {
            int e = e0 + q * 256 + tid;
            d[q] = (e < end) ? dst[e] : -1;
        }
#pragma unroll
        for (int q = 0; q < 4; ++q)
            if (d[q] >= 0) atomicAdd(&hist[d[q] >> BKT_SHIFT], 1);
    }
    __syncthreads();

    for (int i = tid; i < NBKT; i += 256) {
        int h = hist[i];
        base[i] = h ? atomicAdd(&bucketCnt[i], h) : 0;  // reserve range
        hist[i] = 0;                                    // reuse as cursor
    }
    __syncthreads();

    // phase 3: scatter, 4 edges batched (4 stores in flight)
    for (int e0 = beg; e0 < end; e0 += 1024) {
        int d[4], s[4];
#pragma unroll
        for (int q = 0; q < 4; ++q) {
            int e = e0 + q * 256 + tid;
            d[q] = (e < end) ? dst[e] : -1;
            s[q] = (e < end) ? src[e] : 0;
        }
        int r[4], bkt[4];
#pragma unroll
        for (int q = 0; q < 4; ++q) {
            if (d[q] >= 0) {
                bkt[q] = d[q] >> BKT_SHIFT;
                r[q] = base[bkt[q]] + atomicAdd(&hist[bkt[q]], 1);
            }
        }
#pragma unroll
        for (int q = 0; q < 4; ++q) {
            if (d[q] >= 0 && r[q] < BCAP)
                pairs[(size_t)bkt[q] * BCAP + r[q]] =
                    (unsigned)s[q] | ((unsigned)(d[q] & (NPB - 1)) << 20);
        }
    }
}

// ---------------------------------------------------------------------------
// bucket_sort with inline offset computation (bucket_scan folded in)
// ---------------------------------------------------------------------------
__global__ void bucket_sort(const unsigned int* __restrict__ pairs,
                            const int* __restrict__ bucketCnt,
                            int* __restrict__ srcs,
                            int* __restrict__ indptr, int n) {
    __shared__ int hist[NPB];
    __shared__ int offl[NPB];
    __shared__ int cur[NPB];
    __shared__ int red[256];
    __shared__ int lsrc[BCAP];
    int bkt = blockIdx.x;
    int t = threadIdx.x;
    int cnt = min(bucketCnt[bkt], BCAP);

    // ---- compute global offset: sum of clamped counts of lower buckets ----
    int partial = 0;
    for (int j = t; j < bkt; j += 256) partial += min(bucketCnt[j], BCAP);
    red[t] = partial;
    if (t < NPB) hist[t] = 0;
    __syncthreads();
    for (int s = 128; s > 0; s >>= 1) {
        if (t < s) red[t] += red[t + s];
        __syncthreads();
    }
    int boff = red[0];
    if (bkt == NBKT - 1 && t == 0) indptr[n] = boff + cnt;

    const unsigned int* __restrict__ p = pairs + (size_t)bkt * BCAP;
    unsigned int v[BCAP / 256];
#pragma unroll
    for (int i = 0; i < BCAP / 256; ++i) {
        int e = i * 256 + t;
        v[i] = 0u;
        if (e < cnt) {
            v[i] = p[e];
            atomicAdd(&hist[v[i] >> 20], 1);
        }
    }
    __syncthreads();
    if (t < NPB) offl[t] = hist[t];
    __syncthreads();
    for (int off = 1; off < NPB; off <<= 1) {
        int x = 0;
        if (t < NPB && t >= off) x = offl[t - off];
        __syncthreads();
        if (t < NPB && t >= off) offl[t] += x;
        __syncthreads();
    }
    if (t < NPB) {
        int ex = offl[t] - hist[t];   // exclusive
        cur[t] = ex;
        int node = bkt * NPB + t;
        if (node < n) indptr[node] = boff + ex;
    }
    __syncthreads();
#pragma unroll
    for (int i = 0; i < BCAP / 256; ++i) {
        int e = i * 256 + t;
        if (e < cnt) {
            int r = atomicAdd(&cur[v[i] >> 20], 1);
            lsrc[r] = (int)(v[i] & 0xFFFFFu);
        }
    }
    __syncthreads();
    for (int e = t; e < cnt; e += 256) srcs[boff + e] = lsrc[e];
}

// ---------------------------------------------------------------------------
// Pull-mode GAT aggregate v3: 4 dst nodes per wave, 16-lane group per node.
// H gathered in fp8 e4m3 (1 dword / lane-quad, pk-cvt decode). NO atomics.
// MODE 0: concat+elu -> half [n,64]; MODE 1: head-mean+elu -> float [n,16];
// MODE 2: head-mean -> float [n,16]
// ---------------------------------------------------------------------------
template <int MODE, typename TOUT>
__global__ void gat_pull3(const unsigned char* __restrict__ H,
                          const float* __restrict__ AS,
                          const float* __restrict__ AD,
                          const int* __restrict__ indptr,
                          const int* __restrict__ srcs,
                          const float* __restrict__ bias,
                          TOUT* __restrict__ out, int n) {
    int lane = threadIdx.x & 63;
    int grp  = lane >> 4;          // which node of the quad
    int sl   = lane & 15;          // channel-quad index (channels 4sl..4sl+3)
    int head = sl >> 2;            // head of this channel quad
    int wave = (blockIdx.x * blockDim.x + threadIdx.x) >> 6;
    int nwaves = (gridDim.x * blockDim.x) >> 6;

    for (int d0 = wave * 4; d0 < n; d0 += nwaves * 4) {
        int d = d0 + grp;
        if (d < n) {
            float ad  = AD[(size_t)d * 4 + head];
            float asd = AS[(size_t)d * 4 + head];
            // self-loop
            float t0 = asd + ad;
            float wself = __expf(t0 > 0.f ? t0 : 0.2f * t0);
            float den = wself;
            float4 h4s = loadQ4(H + (size_t)d * 64 + sl * 4);
            float4 acc = {wself * h4s.x, wself * h4s.y,
                          wself * h4s.z, wself * h4s.w};

            int beg = indptr[d], end = indptr[d + 1];
            for (int e0 = beg; e0 < end; e0 += 16) {
                int cnt = min(16, end - e0);
                int myS = (sl < cnt) ? srcs[e0 + sl] : 0;  // 16/group, coalesced
                int j = 0;
                for (; j + 4 <= cnt; j += 4) {             // 4 gathers in flight
                    int s[4]; float a[4]; float4 h4[4];
#pragma unroll
                    for (int q = 0; q < 4; ++q)
                        s[q] = __shfl(myS, (grp << 4) + j + q);
#pragma unroll
                    for (int q = 0; q < 4; ++q)
                        a[q] = AS[(size_t)s[q] * 4 + head];
#pragma unroll
                    for (int q = 0; q < 4; ++q)
                        h4[q] = loadQ4(H + (size_t)s[q] * 64 + sl * 4);
#pragma unroll
                    for (int q = 0; q < 4; ++q) {
                        float t = a[q] + ad;
                        float w = __expf(t > 0.f ? t : 0.2f * t);
                        den += w;
                        acc.x += w * h4[q].x; acc.y += w * h4[q].y;
                        acc.z += w * h4[q].z; acc.w += w * h4[q].w;
                    }
                }
                for (; j < cnt; ++j) {                     // tail
                    int s = __shfl(myS, (grp << 4) + j);
                    float t = AS[(size_t)s * 4 + head] + ad;
                    float w = __expf(t > 0.f ? t : 0.2f * t);
                    den += w;
                    float4 h4 = loadQ4(H + (size_t)s * 64 + sl * 4);
                    acc.x += w * h4.x; acc.y += w * h4.y;
                    acc.z += w * h4.z; acc.w += w * h4.w;
                }
            }
            float inv = 1.0f / (den + 1e-16f);
            float4 v = {acc.x * inv, acc.y * inv, acc.z * inv, acc.w * inv};
            if (MODE == 0) {
                float4 b4 = *(const float4*)(bias + sl * 4);
                v.x += b4.x; v.y += b4.y; v.z += b4.z; v.w += b4.w;
                v.x = v.x > 0.f ? v.x : __expf(v.x) - 1.f;
                v.y = v.y > 0.f ? v.y : __expf(v.y) - 1.f;
                v.z = v.z > 0.f ? v.z : __expf(v.z) - 1.f;
                v.w = v.w > 0.f ? v.w : __expf(v.w) - 1.f;
                storeH4((__half*)out + (size_t)d * 64 + sl * 4, v);
            } else {
                // head-mean within group: offsets 4,8 fold the 4 heads
#pragma unroll
                for (int off = 4; off <= 8; off <<= 1) {
                    v.x += __shfl_xor(v.x, off);
                    v.y += __shfl_xor(v.y, off);
                    v.z += __shfl_xor(v.z, off);
                    v.w += __shfl_xor(v.w, off);
                }
                float4 b4 = *(const float4*)(bias + (sl & 3) * 4);
                v.x = 0.25f * v.x + b4.x; v.y = 0.25f * v.y + b4.y;
                v.z = 0.25f * v.z + b4.z; v.w = 0.25f * v.w + b4.w;
                if (MODE == 1) {
                    v.x = v.x > 0.f ? v.x : __expf(v.x) - 1.f;
                    v.y = v.y > 0.f ? v.y : __expf(v.y) - 1.f;
                    v.z = v.z > 0.f ? v.z : __expf(v.z) - 1.f;
                    v.w = v.w > 0.f ? v.w : __expf(v.w) - 1.f;
                }
                if (sl < 4)
                    *(float4*)((float*)out + (size_t)d * 16 + sl * 4) = v;
            }
        }
    }
}

// ---------------------------------------------------------------------------
// Two-stage mean-pool (no global atomics)
// ---------------------------------------------------------------------------
__global__ void pool_stage1(const float* __restrict__ Hf,
                            const int* __restrict__ batch,
                            float* __restrict__ partials, int n) {
    __shared__ float lp[POOL_SLOTS];
    int tid = threadIdx.x;
    for (int i = tid; i < POOL_SLOTS; i += 256) lp[i] = 0.0f;
    __syncthreads();

    int chunk = (n + POOL_BLOCKS - 1) / POOL_BLOCKS;
    int start = blockIdx.x * chunk;
    int end = min(start + chunk, n);
    int c = tid & 15;
    for (int node = start + (tid >> 4); node < end; node += 16) {
        int b = batch[node];
        atomicAdd(&lp[b * 16 + c], Hf[(size_t)node * 16 + c]);
        if (c == 0) atomicAdd(&lp[NB * NG + b], 1.0f);
    }
    __syncthreads();
    float* outp = partials + (size_t)blockIdx.x * POOL_SLOTS;
    for (int i = tid; i < POOL_SLOTS; i += 256) outp[i] = lp[i];
}

__global__ void pool_stage2(const float* __restrict__ partials,
                            float* __restrict__ pooled_counts) {
    int idx = blockIdx.x * blockDim.x + threadIdx.x;
    if (idx >= POOL_SLOTS) return;
    float s = 0.0f;
    for (int j = 0; j < POOL_BLOCKS; ++j)
        s += partials[(size_t)j * POOL_SLOTS + idx];
    pooled_counts[idx] = s;
}

// final MLP head, one thread per graph (64 graphs)
__global__ void mlp_head(const float* __restrict__ pooled_counts,
                         const float* __restrict__ stats,
                         const float* __restrict__ fw1, const float* __restrict__ fb1,
                         const float* __restrict__ fw2, const float* __restrict__ fb2,
                         const float* __restrict__ fw3, const float* __restrict__ fb3,
                         float* __restrict__ out) {
    int g = threadIdx.x;
    if (g >= NB) return;
    const float* pooled = pooled_counts;
    const float* counts = pooled_counts + NB * NG;
    float z[32];
    float inv = 1.0f / fmaxf(counts[g], 1.0f);
#pragma unroll
    for (int c = 0; c < 16; ++c) z[c] = pooled[g * 16 + c] * inv;
#pragma unroll
    for (int c = 0; c < 16; ++c) z[16 + c] = stats[g * 16 + c];

    float z1[32];
#pragma unroll
    for (int j = 0; j < 32; ++j) {
        float acc = fb1[j];
        for (int k = 0; k < 32; ++k) acc += z[k] * fw1[k * 32 + j];
        z1[j] = fmaxf(acc, 0.0f);
    }
    float z2[16];
#pragma unroll
    for (int j = 0; j < 16; ++j) {
        float acc = fb2[j];
        for (int k = 0; k < 32; ++k) acc += z1[k] * fw2[k * 16 + j];
        z2[j] = fmaxf(acc, 0.0f);
    }
    float acc = fb3[0];
#pragma unroll
    for (int k = 0; k < 16; ++k) acc += z2[k] * fw3[k];
    out[g] = acc;
}

extern "C" void kernel_launch(void* const* d_in, const int* in_sizes, int n_in,
                              void* d_out, int out_size, void* d_ws, size_t ws_size,
                              hipStream_t stream) {
    const float* x    = (const float*)d_in[0];
    const float* stats= (const float*)d_in[1];
    const float* W1   = (const float*)d_in[2];
    const float* a1s  = (const float*)d_in[3];
    const float* a1d  = (const float*)d_in[4];
    const float* b1   = (const float*)d_in[5];
    const float* W2   = (const float*)d_in[6];
    const float* a2s  = (const float*)d_in[7];
    const float* a2d  = (const float*)d_in[8];
    const float* b2   = (const float*)d_in[9];
    const float* W3   = (const float*)d_in[10];
    const float* a3s  = (const float*)d_in[11];
    const float* a3d  = (const float*)d_in[12];
    const float* b3   = (const float*)d_in[13];
    const float* fw1  = (const float*)d_in[14];
    const float* fb1  = (const float*)d_in[15];
    const float* fw2  = (const float*)d_in[16];
    const float* fb2  = (const float*)d_in[17];
    const float* fw3  = (const float*)d_in[18];
    const float* fb3  = (const float*)d_in[19];
    const int* ei     = (const int*)d_in[20];
    const int* batch  = (const int*)d_in[21];

    const int n = NNODES, ne = NEDGES;
    const int* srcI = ei;
    const int* dstI = ei + ne;

    // ---- workspace layout ----
    float* ws = (float*)d_ws;
    unsigned char* Hq = (unsigned char*)ws;          // [n,64] fp8 = 6.4MB
    float* B    = (float*)(Hq + (size_t)n * 64);     // 25.6MB region; pairs aliases
    __half* B16 = (__half*)B;                        // layer1 out fp16 [n,64]
    float* C2   = B + (size_t)n * 64;                // [n,16]
    float* AS   = C2 + (size_t)n * 16;               // [n,4]
    float* AD   = AS + (size_t)n * 4;                // [n,4]
    float* PC   = AD + (size_t)n * 4;                // pooled_counts [1088]
    float* PART = PC + POOL_SLOTS;                   // [256][1088]
    int* bucketCnt = (int*)(PART + (size_t)POOL_BLOCKS * POOL_SLOTS); // [NBKT]
    int* indptr    = bucketCnt + NBKT;               // [n+1]
    int* srcs      = indptr + n + 1;                 // [ne]
    unsigned int* pairs = (unsigned int*)B;          // 12.82MB, dead before layer 1

    const int TB = 256;
    const int nlBlocks   = 2048;
    const int pullBlocks = (n + 15) / 16;            // 4 waves/blk × 4 nodes/wave

    // ---- fused: CSR bucket scatter + layer-1 node_linear ----
    hipMemsetAsync(bucketCnt, 0, NBKT * sizeof(int), stream);
    scatter_nl1<<<SCAT_BLOCKS + NL1_BLOCKS, TB, 0, stream>>>(
        srcI, dstI, bucketCnt, pairs, ne,
        x, W1, a1s, a1d, Hq, AS, AD, n);
    bucket_sort<<<NBKT, TB, 0, stream>>>(pairs, bucketCnt, srcs, indptr, n);

    // ---- layer 1 aggregate: 16 -> 4x16 concat, elu (fp16 out) ----
    gat_pull3<0, __half><<<pullBlocks, TB, 0, stream>>>(Hq, AS, AD, indptr, srcs, b1, B16, n);

    // ---- layer 2: 64 (fp16 in, scalar u32 loads) -> head-mean 16, elu ----
    node_linear3h<64><<<nlBlocks, TB, 0, stream>>>((const unsigned*)B16, W2, a2s, a2d, Hq, AS, AD, n);
    gat_pull3<1, float><<<pullBlocks, TB, 0, stream>>>(Hq, AS, AD, indptr, srcs, b2, C2, n);

    // ---- layer 3: 16 -> head-mean 16, no act ----
    node_linear3<16><<<nlBlocks, TB, 0, stream>>>(C2, W3, a3s, a3d, Hq, AS, AD, n);
    gat_pull3<2, float><<<pullBlocks, TB, 0, stream>>>(Hq, AS, AD, indptr, srcs, b3, B, n);

    // ---- two-stage pool + MLP ----
    pool_stage1<<<POOL_BLOCKS, TB, 0, stream>>>(B, batch, PART, n);
    pool_stage2<<<(POOL_SLOTS + TB - 1) / TB, TB, 0, stream>>>(PART, PC);
    mlp_head<<<1, 64, 0, stream>>>(PC, stats, fw1, fb1, fw2, fb2, fw3, fb3,
                                   (float*)d_out);
}